// Round 2
// baseline (633.659 us; speedup 1.0000x reference)
//
#include <hip/hip_runtime.h>

#define HIDDEN  128
#define REDUCED 64
#define NGRAPHS 4096
// Rows fully buffered in registers per block: 8 slots x 24 iters = 192 rows.
// Graph sizes are multinomial(500000, 1/4096): mean 122, sd 11, max~167 < 192.
// Larger graphs fall back to a cache re-read path (correct, just slower).
#define BUF_IT  24

typedef float f4 __attribute__((ext_vector_type(4)));

// ---------------------------------------------------------------------------
// ONE fused kernel: per-graph pool + squeeze-excite MLP + modulate.
// Insight: y[batch[n]] depends only on graph g's own nodes (~62 KB), so one
// block per graph can do everything — and hold the graph's x-rows in
// REGISTERS between the pool pass and the write pass. x is read from HBM
// exactly once; no L3-retention assumption (the previous 2-kernel structure
// gambled that the 244 MiB out-stream wouldn't evict x from Infinity Cache
// before the modulate re-read — nt stores only partially prevented that).
// HBM traffic = 256 MB x-read + 256 MB out-write = the true floor (~81 us).
//
// Layout: 256 threads = 8 row-slots (r = t>>5) x 32 f4-columns (c = t&31).
// Thread t buffers rows lo+r, lo+r+8, ... in buf[24] (96 VGPRs, statically
// indexed fully-unrolled loop so it stays in registers).
// Binary searches in different waves (t==0 / t==64) so their dependent
// load chains overlap.
// ---------------------------------------------------------------------------
__global__ void __launch_bounds__(256, 2)
fused_kernel(const float* __restrict__ x,
             const int* __restrict__ batch,
             const float* __restrict__ W1, const float* __restrict__ b1,
             const float* __restrict__ W2, const float* __restrict__ b2,
             float* __restrict__ out, int n_nodes) {
    const int g = blockIdx.x;
    const int t = threadIdx.x;  // 256
    __shared__ int s_range[2];
    if (t == 0) {
        int lo = 0, hi = n_nodes;
        while (lo < hi) { int mid = (lo + hi) >> 1; if (batch[mid] <  g) lo = mid + 1; else hi = mid; }
        s_range[0] = lo;
    } else if (t == 64) {
        int lo = 0, hi = n_nodes;
        while (lo < hi) { int mid = (lo + hi) >> 1; if (batch[mid] <= g) lo = mid + 1; else hi = mid; }
        s_range[1] = lo;
    }
    __syncthreads();
    const int lo = s_range[0], hi = s_range[1];
    const int r = t >> 5, c = t & 31;

    // ---- pool pass: read x once, buffer rows in registers, accumulate ----
    f4 buf[BUF_IT];
    f4 acc = {0.f, 0.f, 0.f, 0.f};
    const f4* __restrict__ x4 = (const f4*)x;
    #pragma unroll
    for (int i = 0; i < BUF_IT; ++i) {
        const int n = lo + r + 8 * i;
        if (n < hi) {
            const f4 v = __builtin_nontemporal_load(x4 + (size_t)n * 32 + c);
            buf[i] = v;
            acc += v;
        }
    }
    // fallback: rows beyond 192 (none for this input) — accumulate unbuffered
    for (int n = lo + r + 8 * BUF_IT; n < hi; n += 8) {
        acc += x4[(size_t)n * 32 + c];
    }

    __shared__ f4 red[8][32];
    __shared__ float p_s[HIDDEN];
    __shared__ float h_s[REDUCED];
    __shared__ float y_s[HIDDEN];
    red[r][c] = acc;
    __syncthreads();
    if (r == 0) {
        f4 s = red[0][c];
        #pragma unroll
        for (int k = 1; k < 8; ++k) s += red[k][c];
        ((f4*)p_s)[c] = s;
    }
    __syncthreads();

    // ---- MLP: h = relu(p @ W1 + b1) [64]; y = sigmoid(h @ W2 + b2) [128].
    // Same FMA order as the verified kernel; W1/W2 (48 KB) stay L2-resident.
    if (t < REDUCED) {
        float a1 = b1[t];
        #pragma unroll 8
        for (int i = 0; i < HIDDEN; ++i) a1 = fmaf(p_s[i], W1[i * REDUCED + t], a1);
        h_s[t] = a1 > 0.f ? a1 : 0.f;
    }
    __syncthreads();
    if (t < HIDDEN) {
        float a2 = b2[t];
        #pragma unroll 8
        for (int j = 0; j < REDUCED; ++j) a2 = fmaf(h_s[j], W2[j * HIDDEN + t], a2);
        y_s[t] = 1.f / (1.f + __expf(-a2));
    }
    __syncthreads();

    // ---- write pass: out[n] = buf[i] * y — x comes from registers ----
    const f4 yv = ((const f4*)y_s)[c];
    f4* __restrict__ out4 = (f4*)out;
    #pragma unroll
    for (int i = 0; i < BUF_IT; ++i) {
        const int n = lo + r + 8 * i;
        if (n < hi) {
            const f4 v = buf[i];
            f4 o;
            o.x = v.x * yv.x; o.y = v.y * yv.y; o.z = v.z * yv.z; o.w = v.w * yv.w;
            __builtin_nontemporal_store(o, out4 + (size_t)n * 32 + c);
        }
    }
    // fallback: re-read rows beyond 192 from cache (none for this input)
    for (int n = lo + r + 8 * BUF_IT; n < hi; n += 8) {
        const f4 v = x4[(size_t)n * 32 + c];
        f4 o;
        o.x = v.x * yv.x; o.y = v.y * yv.y; o.z = v.z * yv.z; o.w = v.w * yv.w;
        __builtin_nontemporal_store(o, out4 + (size_t)n * 32 + c);
    }
}

extern "C" void kernel_launch(void* const* d_in, const int* in_sizes, int n_in,
                              void* d_out, int out_size, void* d_ws, size_t ws_size,
                              hipStream_t stream) {
    const float* x     = (const float*)d_in[0];
    const int*   batch = (const int*)d_in[1];
    // d_in[2] is the scalar `size` (4096) — fixed-shape problem, hardcoded.
    const float* W1 = (const float*)d_in[3];
    const float* b1 = (const float*)d_in[4];
    const float* W2 = (const float*)d_in[5];
    const float* b2 = (const float*)d_in[6];
    float* out = (float*)d_out;

    const int n_nodes = in_sizes[0] / HIDDEN;

    fused_kernel<<<NGRAPHS, 256, 0, stream>>>(x, batch, W1, b1, W2, b2, out, n_nodes);
}

// Round 3
// 472.452 us; speedup vs baseline: 1.3412x; 1.3412x over previous
//
#include <hip/hip_runtime.h>

#define HIDDEN  128
#define REDUCED 64
#define NGRAPHS 4096

typedef float f4 __attribute__((ext_vector_type(4)));

// ---------------------------------------------------------------------------
// Prologue: starts[g] = lower_bound(batch, g) for g in [0,4096], one thread
// per graph. 4096 parallel binary searches (64 waves) fully overlap their
// ~19-step dependent load chains; upper tree levels are L2-hot. ~3 us.
// Replaces the per-block searches that serialized the old fused kernel
// (2 dependent chains x ~19 x 200-900 cyc at only ~2 resident blocks/CU).
// starts[] is fully written -> workspace poison-safe.
// ---------------------------------------------------------------------------
__global__ void seg_starts_kernel(const int* __restrict__ batch,
                                  int* __restrict__ starts, int n_nodes) {
    const int g = blockIdx.x * blockDim.x + threadIdx.x;
    if (g >= NGRAPHS) return;
    int lo = 0, hi = n_nodes;
    while (lo < hi) { int mid = (lo + hi) >> 1; if (batch[mid] < g) lo = mid + 1; else hi = mid; }
    starts[g] = lo;
    if (g == 0) starts[NGRAPHS] = n_nodes;
}

// ---------------------------------------------------------------------------
// Fused per-graph pool + squeeze-excite MLP + modulate. One 256-thread block
// per graph; thread t -> row-slot r = t>>5 (8 rows in flight), f4-column
// c = t&31.
// Post-mortem of the register-buffer version (314 us, VALUBusy 2.6%,
// VGPR=88 < the 96 the buffer needed): the compiler refused to hold 24 f4
// per thread across the barriers, so the "read x once" plan died in codegen
// and the kernel went latency-bound. New plan: DON'T buffer. Re-read the
// block's 62 KB in the modulate phase -- the re-use distance is one block
// lifetime (~tens of MB of GPU-wide traffic), far under the 256 MiB L3 and
// partially L2-resident, unlike the 2-kernel version whose 244 MB gap
// thrashed. nt out-stores keep the write stream from evicting x; the
// re-read itself is nt (dead after use, evict-first).
// Low VGPR + 5.3 KB LDS -> ~8 blocks/CU of TLP.
// ---------------------------------------------------------------------------
__global__ void __launch_bounds__(256, 4)
fused_kernel(const float* __restrict__ x,
             const int* __restrict__ starts,
             const float* __restrict__ W1, const float* __restrict__ b1,
             const float* __restrict__ W2, const float* __restrict__ b2,
             float* __restrict__ out) {
    const int g = blockIdx.x;
    const int t = threadIdx.x;  // 256
    const int lo = starts[g], hi = starts[g + 1];  // coalesced broadcast
    const int r = t >> 5, c = t & 31;
    const f4* __restrict__ x4 = (const f4*)x;

    // ---- pool pass: allocating loads (we want x resident for the re-read)
    f4 acc = {0.f, 0.f, 0.f, 0.f};
    for (int n = lo + r; n < hi; n += 8) {
        acc += x4[(size_t)n * 32 + c];
    }

    __shared__ f4 red[8][32];
    __shared__ float p_s[HIDDEN];
    __shared__ float h_s[REDUCED];
    __shared__ float y_s[HIDDEN];
    red[r][c] = acc;
    __syncthreads();
    if (r == 0) {
        f4 s = red[0][c];
        #pragma unroll
        for (int k = 1; k < 8; ++k) s += red[k][c];
        ((f4*)p_s)[c] = s;
    }
    __syncthreads();

    // ---- MLP: h = relu(p @ W1 + b1) [64]; y = sigmoid(h @ W2 + b2) [128].
    // Same FMA order as the verified kernel; W1/W2 (48 KB) stay L2-resident.
    if (t < REDUCED) {
        float a1 = b1[t];
        #pragma unroll 8
        for (int i = 0; i < HIDDEN; ++i) a1 = fmaf(p_s[i], W1[i * REDUCED + t], a1);
        h_s[t] = a1 > 0.f ? a1 : 0.f;
    }
    __syncthreads();
    if (t < HIDDEN) {
        float a2 = b2[t];
        #pragma unroll 8
        for (int j = 0; j < REDUCED; ++j) a2 = fmaf(h_s[j], W2[j * HIDDEN + t], a2);
        y_s[t] = 1.f / (1.f + __expf(-a2));
    }
    __syncthreads();

    // ---- modulate pass: re-read (L2/L3-hot, nt = evict-first), nt store
    const f4 yv = ((const f4*)y_s)[c];
    f4* __restrict__ out4 = (f4*)out;
    for (int n = lo + r; n < hi; n += 8) {
        const f4 v = __builtin_nontemporal_load(x4 + (size_t)n * 32 + c);
        f4 o;
        o.x = v.x * yv.x; o.y = v.y * yv.y; o.z = v.z * yv.z; o.w = v.w * yv.w;
        __builtin_nontemporal_store(o, out4 + (size_t)n * 32 + c);
    }
}

extern "C" void kernel_launch(void* const* d_in, const int* in_sizes, int n_in,
                              void* d_out, int out_size, void* d_ws, size_t ws_size,
                              hipStream_t stream) {
    const float* x     = (const float*)d_in[0];
    const int*   batch = (const int*)d_in[1];
    // d_in[2] is the scalar `size` (4096) — fixed-shape problem, hardcoded.
    const float* W1 = (const float*)d_in[3];
    const float* b1 = (const float*)d_in[4];
    const float* W2 = (const float*)d_in[5];
    const float* b2 = (const float*)d_in[6];
    float* out = (float*)d_out;

    const int n_nodes = in_sizes[0] / HIDDEN;

    int* starts = (int*)d_ws;  // 4097 ints, fully written by seg_starts_kernel

    seg_starts_kernel<<<(NGRAPHS + 255) / 256, 256, 0, stream>>>(batch, starts, n_nodes);
    fused_kernel<<<NGRAPHS, 256, 0, stream>>>(x, starts, W1, b1, W2, b2, out);
}

// Round 4
// 462.181 us; speedup vs baseline: 1.3710x; 1.0222x over previous
//
#include <hip/hip_runtime.h>

#define HIDDEN  128
#define REDUCED 64
#define NGRAPHS 4096
// Rows of x staged in LDS per graph: 108*512 B = 54 KB (+4 KB red + 1.3 KB
// MLP buffers = 60.6 KB < 64 KB static limit) -> 2 blocks/CU. Graph sizes
// are multinomial(500000, 1/4096): mean 122, sd 11 -> ~11% of rows overflow
// and take a cache-hot global fallback path instead.
#define ROWCAP  108

typedef float f4 __attribute__((ext_vector_type(4)));

// Fire-and-forget global->LDS DMA, 16 B per lane. LDS dest is wave-uniform
// base + lane*16 (m104); global src is per-lane. No VGPR round-trip, no
// dependency at issue -> a wave can put its entire graph-tile in flight
// before the first byte lands (the plain-load pool loop only pipelined a
// few loads deep, one cause of the 38%-of-peak rate in round 3).
__device__ __forceinline__ void gload_lds16(const void* gsrc, void* ldst) {
    auto g = reinterpret_cast<const __attribute__((address_space(1))) unsigned int*>(
        reinterpret_cast<uintptr_t>(gsrc));
    auto l = reinterpret_cast<__attribute__((address_space(3))) unsigned int*>(
        reinterpret_cast<uintptr_t>(ldst));
    __builtin_amdgcn_global_load_lds(g, l, 16, 0, 0);
}

// ---------------------------------------------------------------------------
// Prologue: starts[g] = lower_bound(batch, g). 4096 parallel binary searches
// fully overlap their dependent load chains; ~3 us. starts fully written ->
// workspace poison-safe.
// ---------------------------------------------------------------------------
__global__ void seg_starts_kernel(const int* __restrict__ batch,
                                  int* __restrict__ starts, int n_nodes) {
    const int g = blockIdx.x * blockDim.x + threadIdx.x;
    if (g >= NGRAPHS) return;
    int lo = 0, hi = n_nodes;
    while (lo < hi) { int mid = (lo + hi) >> 1; if (batch[mid] < g) lo = mid + 1; else hi = mid; }
    starts[g] = lo;
    if (g == 0) starts[NGRAPHS] = n_nodes;
}

// ---------------------------------------------------------------------------
// Fused per-graph pool + squeeze-excite MLP + modulate, LDS-staged.
// Round-3 counters: traffic was already at the floor (FETCH ~= one x pass,
// the modulate re-read hit L3) but rate was 3.07 TB/s = 38% of achievable --
// limited by the L3->CU re-read path + shallow load pipelining. This version
// stages the graph tile in LDS via global_load_lds DMA (deep MLP at issue
// time), so x crosses the cache fabric once and both the pool-reduce and the
// modulate read run at LDS bandwidth.
// Thread map: 256 thr = 8 row-slots (r = t>>5) x 32 f4-cols (c = t&31).
// Stage map: wave w loads row-pairs p = w, w+4, ...; lane l covers row
// 2p+(l>>5), col l&31 -> LDS rows laid contiguously (dest = base + lane*16).
// Both pool and modulate iterate rows nrel = r, r+8, ... with the SAME
// summation order as the verified kernel (LDS loop then global-overflow loop
// carrying nrel over) -> pooled sums bitwise identical, absmax unchanged.
// ---------------------------------------------------------------------------
__global__ void __launch_bounds__(256, 2)
fused_kernel(const float* __restrict__ x,
             const int* __restrict__ starts,
             const float* __restrict__ W1, const float* __restrict__ b1,
             const float* __restrict__ W2, const float* __restrict__ b2,
             float* __restrict__ out) {
    const int g = blockIdx.x;
    const int t = threadIdx.x;  // 256
    const int lo = starts[g], hi = starts[g + 1];
    const int cnt = hi - lo;
    const int staged = cnt < ROWCAP ? cnt : ROWCAP;
    const int r = t >> 5, c = t & 31;
    const int w = t >> 6;           // wave id 0..3
    const int half = (t >> 5) & 1;  // which row of the wave's pair

    __shared__ f4 sbuf[ROWCAP * 32];   // 54 KB graph tile
    __shared__ f4 red[8][32];
    __shared__ float p_s[HIDDEN];
    __shared__ float h_s[REDUCED];
    __shared__ float y_s[HIDDEN];

    const f4* __restrict__ x4 = (const f4*)x;

    // ---- stage: issue the whole tile as DMA before anything else ----
    for (int p = w; 2 * p < staged; p += 4) {
        const int nrel = 2 * p + half;
        if (nrel < staged)  // partial last pair when staged is odd
            gload_lds16(x4 + (size_t)(lo + nrel) * 32 + c, &sbuf[p * 64]);
    }
    asm volatile("s_waitcnt vmcnt(0)" ::: "memory");
    __syncthreads();

    // ---- pool: rows r, r+8, ... ; LDS first, overflow rows from global ----
    f4 acc = {0.f, 0.f, 0.f, 0.f};
    int nrel = r;
    for (; nrel < staged; nrel += 8) acc += sbuf[nrel * 32 + c];
    for (; nrel < cnt;    nrel += 8) acc += x4[(size_t)(lo + nrel) * 32 + c];

    red[r][c] = acc;
    __syncthreads();
    if (r == 0) {
        f4 s = red[0][c];
        #pragma unroll
        for (int k = 1; k < 8; ++k) s += red[k][c];
        ((f4*)p_s)[c] = s;
    }
    __syncthreads();

    // ---- MLP: h = relu(p @ W1 + b1) [64]; y = sigmoid(h @ W2 + b2) [128].
    // Same FMA order as the verified kernel; W1/W2 (48 KB) stay L2-resident.
    if (t < REDUCED) {
        float a1 = b1[t];
        #pragma unroll 8
        for (int i = 0; i < HIDDEN; ++i) a1 = fmaf(p_s[i], W1[i * REDUCED + t], a1);
        h_s[t] = a1 > 0.f ? a1 : 0.f;
    }
    __syncthreads();
    if (t < HIDDEN) {
        float a2 = b2[t];
        #pragma unroll 8
        for (int j = 0; j < REDUCED; ++j) a2 = fmaf(h_s[j], W2[j * HIDDEN + t], a2);
        y_s[t] = 1.f / (1.f + __expf(-a2));
    }
    __syncthreads();

    // ---- modulate: LDS rows (no cache traffic), overflow rows from L2/L3
    // (read moments ago in the pool loop -> hot). nt stores keep the dead
    // out-stream from evicting anything.
    const f4 yv = ((const f4*)y_s)[c];
    f4* __restrict__ out4 = (f4*)out;
    nrel = r;
    for (; nrel < staged; nrel += 8) {
        const f4 v = sbuf[nrel * 32 + c];
        __builtin_nontemporal_store(v * yv, out4 + (size_t)(lo + nrel) * 32 + c);
    }
    for (; nrel < cnt; nrel += 8) {
        const f4 v = x4[(size_t)(lo + nrel) * 32 + c];
        __builtin_nontemporal_store(v * yv, out4 + (size_t)(lo + nrel) * 32 + c);
    }
}

extern "C" void kernel_launch(void* const* d_in, const int* in_sizes, int n_in,
                              void* d_out, int out_size, void* d_ws, size_t ws_size,
                              hipStream_t stream) {
    const float* x     = (const float*)d_in[0];
    const int*   batch = (const int*)d_in[1];
    // d_in[2] is the scalar `size` (4096) — fixed-shape problem, hardcoded.
    const float* W1 = (const float*)d_in[3];
    const float* b1 = (const float*)d_in[4];
    const float* W2 = (const float*)d_in[5];
    const float* b2 = (const float*)d_in[6];
    float* out = (float*)d_out;

    const int n_nodes = in_sizes[0] / HIDDEN;

    int* starts = (int*)d_ws;  // 4097 ints, fully written by seg_starts_kernel

    seg_starts_kernel<<<(NGRAPHS + 255) / 256, 256, 0, stream>>>(batch, starts, n_nodes);
    fused_kernel<<<NGRAPHS, 256, 0, stream>>>(x, starts, W1, b1, W2, b2, out);
}